// Round 1
// baseline (243.973 us; speedup 1.0000x reference)
//
#include <hip/hip_runtime.h>
#include <math.h>

#define NB 8
#define NN 2048
#define IN_DIM 256
#define OUT_DIM 64
#define ALPHA 0.2f
#define JSPLIT 8

typedef __attribute__((ext_vector_type(8))) short bf16x8;
typedef __attribute__((ext_vector_type(4))) float f32x4;
typedef __attribute__((ext_vector_type(4))) int i32x4;

// float -> bf16 (RNE), bit trick (no NaN inputs here)
__device__ __forceinline__ unsigned short f2bf(float x) {
    union { float f; unsigned u; } v; v.f = x;
    unsigned r = v.u + 0x7FFF + ((v.u >> 16) & 1);
    return (unsigned short)(r >> 16);
}

// pack 2 f32 -> 2 bf16 (RNE), single HW instr; numerically == f2bf
__device__ __forceinline__ unsigned cvt_pk_bf16(float lo, float hi) {
    unsigned r;
    asm("v_cvt_pk_bf16_f32 %0, %1, %2" : "=v"(r) : "v"(lo), "v"(hi));
    return r;
}

// ---------------------------------------------------------------------------
// Kernel 1: Wh = h@W via bf16 MFMA. Outputs: Whbt (bf16, layout [b][d][j] so
// kernel-2 B-frags are 16B contiguous per lane), s1 = Wh@a1, s2 = Wh@a2.
// W staged once per block into LDS TRANSPOSED (Wt[n][k], pad 264) so B-frag
// reads are ds_read_b128.
// Grid 256 blocks x 256 thr; wave = one 16-row i-tile, block = 64 rows.
// ---------------------------------------------------------------------------
#define WT_STRIDE 264   // bf16 elems; 528B rows (16B aligned)
__global__ __launch_bounds__(256) void wh_kernel(const float* __restrict__ h,
                                                 const float* __restrict__ W,
                                                 const float* __restrict__ a,
                                                 unsigned short* __restrict__ Whbt,
                                                 float* __restrict__ s1,
                                                 float* __restrict__ s2) {
    __shared__ unsigned short Wt[OUT_DIM * WT_STRIDE];   // ~33 KB
    const int t = threadIdx.x;

    // stage W (coalesced f32 reads) -> Wt[n][k] bf16
    #pragma unroll 8
    for (int rep = 0; rep < 64; ++rep) {
        const int id = rep * 256 + t;          // 0..16383
        const int k = id >> 6, n = id & 63;
        Wt[n * WT_STRIDE + k] = f2bf(W[id]);
    }
    __syncthreads();

    const int lane = t & 63, wv = t >> 6;
    const int m = lane & 15, quad = lane >> 4;
    const long gr0 = (long)(blockIdx.x * 4 + wv) * 16;   // global row base

    f32x4 acc[4];
    #pragma unroll
    for (int nt = 0; nt < 4; ++nt) acc[nt] = (f32x4){0.f, 0.f, 0.f, 0.f};

    #pragma unroll
    for (int ks = 0; ks < 8; ++ks) {
        const int k0 = ks * 32;
        // A-frag: h[i = gr0+m][k0 + quad*8 .. +7]  (per-lane distinct, 32B)
        const float* hp = h + (gr0 + m) * IN_DIM + k0 + quad * 8;
        const float4 ha = *(const float4*)hp;
        const float4 hb = *(const float4*)(hp + 4);
        union { bf16x8 v; unsigned u32[4]; } af;
        af.u32[0] = cvt_pk_bf16(ha.x, ha.y);
        af.u32[1] = cvt_pk_bf16(ha.z, ha.w);
        af.u32[2] = cvt_pk_bf16(hb.x, hb.y);
        af.u32[3] = cvt_pk_bf16(hb.z, hb.w);
        #pragma unroll
        for (int nt = 0; nt < 4; ++nt) {
            // B-frag: Wt[n = nt*16+m][k0 + quad*8 .. +7] -> ds_read_b128
            const bf16x8 bf_ = *(const bf16x8*)(const void*)
                &Wt[(nt * 16 + m) * WT_STRIDE + k0 + quad * 8];
            acc[nt] = __builtin_amdgcn_mfma_f32_16x16x32_bf16(af.v, bf_, acc[nt], 0, 0, 0);
        }
    }

    // ---- epilogue.  C layout: col=lane&15 (d within tile), row=quad*4+reg (i) ----
    const int b  = (int)(gr0 >> 11);
    const int ib = (int)(gr0 & 2047);          // within-batch row base

    // Whbt[b][d][j]: pack 4 consecutive i (regs) as ushort4
    #pragma unroll
    for (int nt = 0; nt < 4; ++nt) {
        ushort4 w4;
        w4.x = f2bf(acc[nt][0]); w4.y = f2bf(acc[nt][1]);
        w4.z = f2bf(acc[nt][2]); w4.w = f2bf(acc[nt][3]);
        *(ushort4*)&Whbt[((long)(b * OUT_DIM + nt * 16 + m) << 11) + ib + quad * 4] = w4;
    }

    // s1/s2: per-lane partial over its 4 cols, reduce across the 16-lane col group
    float a1v[4], a2v[4];
    #pragma unroll
    for (int nt = 0; nt < 4; ++nt) {
        a1v[nt] = a[nt * 16 + m];
        a2v[nt] = a[OUT_DIM + nt * 16 + m];
    }
    #pragma unroll
    for (int reg = 0; reg < 4; ++reg) {
        float p1 = 0.f, p2 = 0.f;
        #pragma unroll
        for (int nt = 0; nt < 4; ++nt) {
            p1 += acc[nt][reg] * a1v[nt];
            p2 += acc[nt][reg] * a2v[nt];
        }
        #pragma unroll
        for (int off = 1; off < 16; off <<= 1) {   // lanes quad*16+m, m-group
            p1 += __shfl_xor(p1, off, 64);
            p2 += __shfl_xor(p2, off, 64);
        }
        if (m == 0) {
            s1[gr0 + quad * 4 + reg] = p1;
            s2[gr0 + quad * 4 + reg] = p2;
        }
    }
}

// ---------------------------------------------------------------------------
// Kernel 2: masked softmax (no max-subtraction; scores bounded) + P@Wh via
// bf16 MFMA.  NO LDS AT ALL: P is computed directly in the MFMA A-fragment
// lane layout (lane (m,quad) owns row i0+m, j = j0+quad*8..+7), packed to
// bf16 in-register via v_cvt_pk_bf16_f32.  Per 32-j step:
//   2x nontemporal dwordx4 adj loads (prefetched 1 step ahead) +
//   2x f32x4 s2 loads (prefetched) + 4x 16B Whbt B-frags (L2-hot) +
//   8x leakyrelu/exp/mask + 4 cvt_pk + 4 MFMA.
// Grid: NB * (NN/64) * JSPLIT = 2048 blocks x 4 waves; zero barriers.
// Partials to part/lpart; finalize divides.
// ---------------------------------------------------------------------------
__global__ __launch_bounds__(256) void attn_kernel(const int* __restrict__ adj,
                                                   const unsigned short* __restrict__ Whbt,
                                                   const float* __restrict__ s1,
                                                   const float* __restrict__ s2,
                                                   float* __restrict__ part,
                                                   float* __restrict__ lpart) {
    const int t = threadIdx.x, lane = t & 63, wv = t >> 6;

    const int bid = blockIdx.x;
    const int js  = bid & (JSPLIT - 1);
    const int itg = (bid >> 3) & 31;
    const int b   = bid >> 8;
    const int i0  = itg * 64 + wv * 16;       // within-batch row base (16 rows)
    const int jlo = js * (NN / JSPLIT);       // 256-wide j slice

    const int m = lane & 15, quad = lane >> 4;   // MFMA lane map (rows x k-quad)

    const float s1v = s1[b * NN + i0 + m];

    f32x4 acc[4];
    #pragma unroll
    for (int nt = 0; nt < 4; ++nt) acc[nt] = (f32x4){0.f, 0.f, 0.f, 0.f};
    float lacc = 0.f;

    const int* adjp = adj + (long)b * NN * NN + (long)(i0 + m) * NN + jlo + quad * 8;
    const float* s2p = s2 + b * NN + jlo + quad * 8;
    const unsigned short* wbase = Whbt + ((long)(b * OUT_DIM) << 11) + jlo + quad * 8;

    // prefetch step 0 (adj: nontemporal — streamed once, keep Whbt L2-resident)
    i32x4 av0 = __builtin_nontemporal_load((const i32x4*)adjp);
    i32x4 av1 = __builtin_nontemporal_load((const i32x4*)(adjp + 4));
    f32x4 sv0 = *(const f32x4*)s2p;
    f32x4 sv1 = *(const f32x4*)(s2p + 4);

    const int NSTEP = NN / JSPLIT / 32;       // 8
    for (int ks = 0; ks < NSTEP; ++ks) {
        const int j0 = ks * 32;

        // B-frags for this step (issue early; consumed by MFMA at step end)
        bf16x8 bfr[4];
        #pragma unroll
        for (int nt = 0; nt < 4; ++nt)
            bfr[nt] = *(const bf16x8*)(const void*)
                &wbase[((long)(nt * 16 + m) << 11) + j0];

        // grab prefetched operands, then issue next step's prefetch
        const i32x4 a0 = av0, a1 = av1;
        const f32x4 t0 = sv0, t1 = sv1;
        const int jn = (ks + 1 < NSTEP) ? j0 + 32 : j0;
        av0 = __builtin_nontemporal_load((const i32x4*)(adjp + jn));
        av1 = __builtin_nontemporal_load((const i32x4*)(adjp + jn + 4));
        sv0 = *(const f32x4*)(s2p + jn);
        sv1 = *(const f32x4*)(s2p + jn + 4);

        // P for this lane's 8 j's, directly in A-frag order
        float p[8];
        #pragma unroll
        for (int u = 0; u < 4; ++u) {
            float e = s1v + t0[u];
            e = fmaxf(e, ALPHA * e);            // leaky_relu, branchless
            const float ex = __expf(e);
            p[u] = (a0[u] != 0) ? ex : 0.f;
        }
        #pragma unroll
        for (int u = 0; u < 4; ++u) {
            float e = s1v + t1[u];
            e = fmaxf(e, ALPHA * e);
            const float ex = __expf(e);
            p[4 + u] = (a1[u] != 0) ? ex : 0.f;
        }
        lacc += ((p[0] + p[1]) + (p[2] + p[3])) + ((p[4] + p[5]) + (p[6] + p[7]));

        union { bf16x8 v; unsigned u32[4]; } af;
        af.u32[0] = cvt_pk_bf16(p[0], p[1]);
        af.u32[1] = cvt_pk_bf16(p[2], p[3]);
        af.u32[2] = cvt_pk_bf16(p[4], p[5]);
        af.u32[3] = cvt_pk_bf16(p[6], p[7]);

        #pragma unroll
        for (int nt = 0; nt < 4; ++nt)
            acc[nt] = __builtin_amdgcn_mfma_f32_16x16x32_bf16(af.v, bfr[nt], acc[nt], 0, 0, 0);
    }

    // ---- l partials: sum this lane's j-subset over quads (rows = m) ----
    lacc += __shfl_xor(lacc, 16, 64);
    lacc += __shfl_xor(lacc, 32, 64);
    if (quad == 0)
        lpart[js * (NB * NN) + b * NN + i0 + m] = lacc;

    // ---- out partials.  C layout: i = i0+quad*4+reg, d = nt*16+m ----
    float* pp = part + (long)js * ((long)NB * NN * OUT_DIM)
                     + ((long)(b * NN + i0) << 6);
    #pragma unroll
    for (int nt = 0; nt < 4; ++nt)
        #pragma unroll
        for (int reg = 0; reg < 4; ++reg)
            pp[(quad * 4 + reg) * OUT_DIM + nt * 16 + m] = acc[nt][reg];
}

// ---------------------------------------------------------------------------
// Kernel 3: out = (sum_js part) / (sum_js lpart), float4 coalesced.
// ---------------------------------------------------------------------------
__global__ __launch_bounds__(256) void finalize_kernel(const float* __restrict__ part,
                                                       const float* __restrict__ lpart,
                                                       float* __restrict__ out) {
    const int idx = blockIdx.x * 256 + threadIdx.x;   // float4 index
    const int row = idx >> 4;
    float l = 0.f;
    #pragma unroll
    for (int s = 0; s < JSPLIT; ++s) l += lpart[s * (NB * NN) + row];
    float4 v = make_float4(0.f, 0.f, 0.f, 0.f);
    const float4* p4 = (const float4*)part;
    #pragma unroll
    for (int s = 0; s < JSPLIT; ++s) {
        const float4 p = p4[(long)s * ((long)NB * NN * OUT_DIM / 4) + idx];
        v.x += p.x; v.y += p.y; v.z += p.z; v.w += p.w;
    }
    const float inv = 1.f / l;
    v.x *= inv; v.y *= inv; v.z *= inv; v.w *= inv;
    ((float4*)out)[idx] = v;
}

// ---------------------------------------------------------------------------
extern "C" void kernel_launch(void* const* d_in, const int* in_sizes, int n_in,
                              void* d_out, int out_size, void* d_ws, size_t ws_size,
                              hipStream_t stream) {
    const float* h   = (const float*)d_in[0];
    const int*   adj = (const int*)d_in[1];
    const float* W   = (const float*)d_in[2];
    const float* a   = (const float*)d_in[3];
    float* out = (float*)d_out;

    float* s1    = (float*)d_ws;                         // 16K f32
    float* s2    = s1 + NB * NN;                         // 16K f32
    float* lpart = s2 + NB * NN;                         // 128K f32
    float* part  = lpart + JSPLIT * NB * NN;             // 8M f32 = 32 MB
    unsigned short* Whbt = (unsigned short*)(part + (long)JSPLIT * NB * NN * OUT_DIM); // 1M bf16 = 2 MB

    wh_kernel<<<NB * NN / 64, 256, 0, stream>>>(h, W, a, Whbt, s1, s2);
    attn_kernel<<<NB * (NN / 64) * JSPLIT, 256, 0, stream>>>(adj, Whbt, s1, s2, part, lpart);
    finalize_kernel<<<NB * NN * OUT_DIM / 4 / 256, 256, 0, stream>>>(part, lpart, out);
}